// Round 1
// baseline (3179.390 us; speedup 1.0000x reference)
//
#include <hip/hip_runtime.h>
#include <hip/hip_bf16.h>
#include <hip/hip_cooperative_groups.h>
#include <cstdint>
#include <cstddef>

namespace cg = cooperative_groups;

// Problem dims (fixed)
#define TSTEPS 128
#define BATCH  64
#define DDIM   1024
#define HDIM   1024
#define HADIM  128
#define VOCAB  10000
#define MROWS  (TSTEPS * BATCH)   // 8192

typedef __attribute__((ext_vector_type(8))) short bf16x8;
typedef __attribute__((ext_vector_type(4))) float f32x4;

__device__ __forceinline__ unsigned short f2bf(float x) {
    unsigned int u = __float_as_uint(x);
    unsigned int r = (u + 0x7fffu + ((u >> 16) & 1u)) >> 16;
    return (unsigned short)r;
}

// ---------------- transpose + cast fp32 -> bf16 (W: RxC -> Wt: CxR) ----------------
__global__ __launch_bounds__(256) void transpose_cast(const float* __restrict__ W,
                                                      unsigned short* __restrict__ Wt,
                                                      int R, int C) {
    __shared__ float tile[32][33];
    int tc = blockIdx.x * 32;   // col base in W
    int tr = blockIdx.y * 32;   // row base in W
    int tid = threadIdx.x;
    for (int i = 0; i < 4; i++) {
        int idx = tid + i * 256;
        int r = idx >> 5, c = idx & 31;
        float v = 0.f;
        if (tr + r < R && tc + c < C) v = W[(size_t)(tr + r) * C + tc + c];
        tile[r][c] = v;
    }
    __syncthreads();
    for (int i = 0; i < 4; i++) {
        int idx = tid + i * 256;
        int r = idx >> 5, c = idx & 31;   // r = row of Wt (= col of W)
        if (tc + r < C && tr + c < R)
            Wt[(size_t)(tc + r) * R + tr + c] = f2bf(tile[c][r]);
    }
}

// ---------------- gather embedding rows + cast to bf16 ----------------
__global__ __launch_bounds__(256) void gather_cast(const int* __restrict__ tok,
                                                   const float* __restrict__ emb,
                                                   unsigned short* __restrict__ xb) {
    int i = blockIdx.x;               // 0..8191 (t*64+b)
    int t = tok[i];
    const float4* src = (const float4*)(emb + (size_t)t * DDIM);
    float4 v = src[threadIdx.x];
    ushort4 o;
    o.x = f2bf(v.x); o.y = f2bf(v.y); o.z = f2bf(v.z); o.w = f2bf(v.w);
    ((ushort4*)(xb + (size_t)i * DDIM))[threadIdx.x] = o;
}

// ---------------- generic C = A @ Bt^T + bias, bf16 in / fp32 out ----------------
// A: MxK bf16 row-major; Bt: NxK bf16 row-major; C: MxN fp32. K multiple of 32, M multiple of 64.
__global__ __launch_bounds__(256) void gemm_bt_bias(const unsigned short* __restrict__ A,
                                                    const unsigned short* __restrict__ Bt,
                                                    const float* __restrict__ bias,
                                                    float* __restrict__ C,
                                                    int M, int N, int K) {
    __shared__ unsigned short As[64 * 40];
    __shared__ unsigned short Bs[64 * 40];
    int rowBase = blockIdx.y * 64;
    int colBase = blockIdx.x * 64;
    int tid = threadIdx.x;
    int wave = tid >> 6, lane = tid & 63;
    int wr = wave >> 1, wc = wave & 1;
    int quad = lane >> 4, lr = lane & 15;
    int ldRow = tid >> 2;            // 0..63
    int ldK = (tid & 3) * 8;         // 0,8,16,24
    bool bvalid = (colBase + ldRow) < N;
    const unsigned short* Ag = A + (size_t)(rowBase + ldRow) * K + ldK;
    const unsigned short* Bg = Bt + (size_t)(colBase + ldRow) * K + ldK;

    f32x4 acc[2][2] = {};
    for (int k0 = 0; k0 < K; k0 += 32) {
        uint4 av = *(const uint4*)(Ag + k0);
        uint4 bv = {};
        if (bvalid) bv = *(const uint4*)(Bg + k0);
        __syncthreads();
        *(uint4*)(As + ldRow * 40 + ldK) = av;
        *(uint4*)(Bs + ldRow * 40 + ldK) = bv;
        __syncthreads();
        bf16x8 a0 = *(const bf16x8*)(As + (wr * 32 + lr) * 40 + quad * 8);
        bf16x8 a1 = *(const bf16x8*)(As + (wr * 32 + 16 + lr) * 40 + quad * 8);
        bf16x8 b0 = *(const bf16x8*)(Bs + (wc * 32 + lr) * 40 + quad * 8);
        bf16x8 b1 = *(const bf16x8*)(Bs + (wc * 32 + 16 + lr) * 40 + quad * 8);
        acc[0][0] = __builtin_amdgcn_mfma_f32_16x16x32_bf16(a0, b0, acc[0][0], 0, 0, 0);
        acc[0][1] = __builtin_amdgcn_mfma_f32_16x16x32_bf16(a0, b1, acc[0][1], 0, 0, 0);
        acc[1][0] = __builtin_amdgcn_mfma_f32_16x16x32_bf16(a1, b0, acc[1][0], 0, 0, 0);
        acc[1][1] = __builtin_amdgcn_mfma_f32_16x16x32_bf16(a1, b1, acc[1][1], 0, 0, 0);
    }
    for (int mi = 0; mi < 2; mi++)
        for (int ni = 0; ni < 2; ni++) {
            int col = colBase + wc * 32 + ni * 16 + lr;
            if (col < N) {
                float b = bias[col];
                for (int r = 0; r < 4; r++) {
                    int row = rowBase + wr * 32 + mi * 16 + quad * 4 + r;
                    C[(size_t)row * N + col] = acc[mi][ni][r] + b;
                }
            }
        }
}

// ---------------- h0 recurrence + gates (fp32 exact, one WG per batch row) ----------------
__global__ __launch_bounds__(128) void h0_chain(const float* __restrict__ Xa,   // (T*B) x 128
                                                const float* __restrict__ Wah,  // 128 x 128
                                                const float* __restrict__ Wa,   // 128 x 2
                                                const float* __restrict__ ba,   // 2
                                                float2* __restrict__ ns) {      // T*B
    int b = blockIdx.x;      // batch 0..63
    int j = threadIdx.x;     // 0..127
    __shared__ float WahS[HADIM * HADIM];
    __shared__ float h0s[HADIM];
    __shared__ float red[4];
    for (int i = j; i < HADIM * HADIM; i += 128) WahS[i] = Wah[i];
    h0s[j] = 0.f;
    float wa0 = Wa[j * 2 + 0], wa1 = Wa[j * 2 + 1];
    float ba0 = ba[0], ba1 = ba[1];
    __syncthreads();
    for (int t = 0; t < TSTEPS; t++) {
        float acc = Xa[((size_t)t * BATCH + b) * HADIM + j];
        for (int k = 0; k < HADIM; k++) acc += h0s[k] * WahS[k * HADIM + j];
        float h0n = tanhf(acc);
        float p0 = h0n * wa0, p1 = h0n * wa1;
        for (int off = 32; off > 0; off >>= 1) {
            p0 += __shfl_down(p0, off);
            p1 += __shfl_down(p1, off);
        }
        int wv = j >> 6;
        if ((j & 63) == 0) { red[wv * 2 + 0] = p0; red[wv * 2 + 1] = p1; }
        __syncthreads();
        float n = 1.f / (1.f + __expf(-(red[0] + red[2] + ba0)));
        float s = 1.f / (1.f + __expf(-(red[1] + red[3] + ba1)));
        if (j == 0) ns[t * BATCH + b] = make_float2(n, s);
        h0s[j] = h0n;
        __syncthreads();
    }
}

// ---------------- fused h1 recurrence: ALL 128 steps in one cooperative launch ----------------
// grid = 32 blocks x 512 threads (8 waves). Block cg owns output cols [cg*32, cg*32+32).
// Wave w: m-tile = w&3 (batch rows m*16..m*16+16), n-tile = w>>2 (16 cols).
// Weight fragments (16 cols x 1024 K of WhhT) are LOOP-INVARIANT over t and live in
// 128 VGPRs (bfr[32]), loaded ONCE. Per step: 32 A-frag loads (8-deep prefetch ring)
// + 32 MFMAs + fused gate epilogue, then grid.sync().
__global__ __launch_bounds__(512, 2) void rnn_fused(
        const unsigned short* __restrict__ WhhT,  // 1024x1024 bf16 (N x K)
        const float* __restrict__ Xi,             // (T*B) x 1024 fp32
        const float2* __restrict__ ns,            // T*B gates
        unsigned short* __restrict__ hs,          // (T*B) x 1024 bf16 (output + carry)
        float* __restrict__ h1f) {                // 64x1024 fp32 (final h1)
    cg::grid_group grid = cg::this_grid();
    int cgid = blockIdx.x;            // 0..31
    int wave = threadIdx.x >> 6;      // 0..7
    int lane = threadIdx.x & 63;
    int m  = wave & 3;                // row tile
    int nt = wave >> 2;               // col sub-tile
    int quad = lane >> 4, lr = lane & 15;
    int colBase = cgid * 32 + nt * 16;

    // Preload B fragments once (registers): lane holds Bt[colBase+lr][kc*32+quad*8 ..+8]
    bf16x8 bfr[32];
    {
        const unsigned short* Bg = WhhT + (size_t)(colBase + lr) * HDIM + quad * 8;
        #pragma unroll
        for (int kc = 0; kc < 32; kc++)
            bfr[kc] = *(const bf16x8*)(Bg + kc * 32);
    }
    const int col  = colBase + lr;
    const int arow = m * 16 + lr;     // A row this lane loads fragments from

    for (int t = 0; t < TSTEPS; t++) {
        f32x4 acc = {};
        if (t > 0) {
            const unsigned short* Ag = hs + ((size_t)(t - 1) * BATCH + arow) * HDIM + quad * 8;
            uint4 apf[8];                       // 8-deep prefetch ring (static idx via unroll)
            #pragma unroll
            for (int i = 0; i < 8; i++) apf[i] = *(const uint4*)(Ag + i * 32);
            #pragma unroll
            for (int kc = 0; kc < 32; kc++) {
                uint4 av = apf[kc & 7];
                if (kc < 24) apf[kc & 7] = *(const uint4*)(Ag + (kc + 8) * 32);
                acc = __builtin_amdgcn_mfma_f32_16x16x32_bf16(
                          *(const bf16x8*)&av, bfr[kc], acc, 0, 0, 0);
            }
        }
        // epilogue: pre = acc + Xi_t ; gated nonlinearity ; write hs[t] (+ final h1)
        const float*  Xt  = Xi + (size_t)t * BATCH * HDIM;
        const float2* nst = ns + t * BATCH;
        unsigned short* ht = hs + (size_t)t * BATCH * HDIM;
        #pragma unroll
        for (int r = 0; r < 4; r++) {
            int brow = m * 16 + quad * 4 + r;
            float2 g = nst[brow];
            float pre = acc[r] + Xt[(size_t)brow * HDIM + col];
            float z = g.x * pre;
            float th = tanhf(z);
            float sg = 1.f / (1.f + __expf(-z));
            float h1n = (1.f - g.y) * th + g.y * sg;
            ht[(size_t)brow * HDIM + col] = f2bf(h1n);
            if (t == TSTEPS - 1) h1f[(size_t)brow * HDIM + col] = h1n;
        }
        grid.sync();
    }
}

extern "C" void kernel_launch(void* const* d_in, const int* in_sizes, int n_in,
                              void* d_out, int out_size, void* d_ws, size_t ws_size,
                              hipStream_t stream) {
    const int*   tokens = (const int*)d_in[0];
    const float* emb    = (const float*)d_in[1];
    const float* Wax    = (const float*)d_in[2];
    const float* Wah    = (const float*)d_in[3];
    const float* bah    = (const float*)d_in[4];
    const float* Wa     = (const float*)d_in[5];
    const float* ba     = (const float*)d_in[6];
    const float* Wih    = (const float*)d_in[7];
    const float* Whh    = (const float*)d_in[8];
    const float* bh     = (const float*)d_in[9];
    const float* Wd     = (const float*)d_in[10];
    const float* bd     = (const float*)d_in[11];
    float* out = (float*)d_out;

    char* ws = (char*)d_ws;
    size_t off = 0;
    auto alloc = [&](size_t bytes) -> void* {
        void* p = ws + off;
        off += (bytes + 255) & ~(size_t)255;
        return p;
    };
    unsigned short* WihT = (unsigned short*)alloc((size_t)HDIM * DDIM * 2);      // 2 MB
    unsigned short* WaxT = (unsigned short*)alloc((size_t)HADIM * DDIM * 2);     // 256 KB
    unsigned short* WhhT = (unsigned short*)alloc((size_t)HDIM * HDIM * 2);      // 2 MB
    unsigned short* WdT  = (unsigned short*)alloc((size_t)VOCAB * HDIM * 2);     // ~20 MB
    unsigned short* xb   = (unsigned short*)alloc((size_t)MROWS * DDIM * 2);     // 16 MB
    float*          Xi   = (float*)alloc((size_t)MROWS * HDIM * 4);              // 32 MB
    float*          Xa   = (float*)alloc((size_t)MROWS * HADIM * 4);             // 4 MB
    unsigned short* hs   = (unsigned short*)alloc((size_t)MROWS * HDIM * 2);     // 16 MB
    float2*         ns   = (float2*)alloc((size_t)TSTEPS * BATCH * 8);           // 64 KB

    // 1. weight transposes (fp32 -> bf16, B^T layout for GEMMs)
    transpose_cast<<<dim3(32, 32), 256, 0, stream>>>(Wih, WihT, DDIM, HDIM);
    transpose_cast<<<dim3(4, 32), 256, 0, stream>>>(Wax, WaxT, DDIM, HADIM);
    transpose_cast<<<dim3(32, 32), 256, 0, stream>>>(Whh, WhhT, HDIM, HDIM);
    transpose_cast<<<dim3(313, 32), 256, 0, stream>>>(Wd, WdT, HDIM, VOCAB);
    // 2. gather x = emb[tokens] -> bf16
    gather_cast<<<MROWS, 256, 0, stream>>>(tokens, emb, xb);
    // 3. Xi = x @ Wih + bh ; Xa = x @ Wax + bah
    gemm_bt_bias<<<dim3(HDIM / 64, MROWS / 64), 256, 0, stream>>>(xb, WihT, bh, Xi, MROWS, HDIM, DDIM);
    gemm_bt_bias<<<dim3(HADIM / 64, MROWS / 64), 256, 0, stream>>>(xb, WaxT, bah, Xa, MROWS, HADIM, DDIM);
    // 4. h0 chain + gates (all timesteps)
    h0_chain<<<BATCH, 128, 0, stream>>>(Xa, Wah, Wa, ba, ns);
    // 5. fused h1 recurrence: one cooperative launch for all 128 steps
    {
        float* h1fin = out + (size_t)MROWS * VOCAB;
        const unsigned short* WhhT_a = WhhT;
        const float*  Xi_a = Xi;
        const float2* ns_a = ns;
        unsigned short* hs_a = hs;
        void* args[] = { (void*)&WhhT_a, (void*)&Xi_a, (void*)&ns_a, (void*)&hs_a, (void*)&h1fin };
        hipLaunchCooperativeKernel((const void*)rnn_fused, dim3(32), dim3(512), args, 0, stream);
    }
    // 6. decoded = hs @ Wd + bd
    gemm_bt_bias<<<dim3((VOCAB + 63) / 64, MROWS / 64), 256, 0, stream>>>(hs, WdT, bd, out, MROWS, VOCAB, HDIM);
}

// Round 2
// 2424.231 us; speedup vs baseline: 1.3115x; 1.3115x over previous
//
#include <hip/hip_runtime.h>
#include <hip/hip_bf16.h>
#include <cstdint>
#include <cstddef>

// Problem dims (fixed)
#define TSTEPS 128
#define BATCH  64
#define DDIM   1024
#define HDIM   1024
#define HADIM  128
#define VOCAB  10000
#define MROWS  (TSTEPS * BATCH)   // 8192
#define NBLK   32                 // blocks in the fused recurrence grid

typedef __attribute__((ext_vector_type(8))) short bf16x8;
typedef __attribute__((ext_vector_type(4))) float f32x4;

__device__ __forceinline__ unsigned short f2bf(float x) {
    unsigned int u = __float_as_uint(x);
    unsigned int r = (u + 0x7fffu + ((u >> 16) & 1u)) >> 16;
    return (unsigned short)r;
}

// ---------------- transpose + cast fp32 -> bf16 (W: RxC -> Wt: CxR) ----------------
__global__ __launch_bounds__(256) void transpose_cast(const float* __restrict__ W,
                                                      unsigned short* __restrict__ Wt,
                                                      int R, int C) {
    __shared__ float tile[32][33];
    int tc = blockIdx.x * 32;   // col base in W
    int tr = blockIdx.y * 32;   // row base in W
    int tid = threadIdx.x;
    for (int i = 0; i < 4; i++) {
        int idx = tid + i * 256;
        int r = idx >> 5, c = idx & 31;
        float v = 0.f;
        if (tr + r < R && tc + c < C) v = W[(size_t)(tr + r) * C + tc + c];
        tile[r][c] = v;
    }
    __syncthreads();
    for (int i = 0; i < 4; i++) {
        int idx = tid + i * 256;
        int r = idx >> 5, c = idx & 31;   // r = row of Wt (= col of W)
        if (tc + r < C && tr + c < R)
            Wt[(size_t)(tc + r) * R + tr + c] = f2bf(tile[c][r]);
    }
}

// ---------------- gather embedding rows + cast to bf16 ----------------
__global__ __launch_bounds__(256) void gather_cast(const int* __restrict__ tok,
                                                   const float* __restrict__ emb,
                                                   unsigned short* __restrict__ xb) {
    int i = blockIdx.x;               // 0..8191 (t*64+b)
    int t = tok[i];
    const float4* src = (const float4*)(emb + (size_t)t * DDIM);
    float4 v = src[threadIdx.x];
    ushort4 o;
    o.x = f2bf(v.x); o.y = f2bf(v.y); o.z = f2bf(v.z); o.w = f2bf(v.w);
    ((ushort4*)(xb + (size_t)i * DDIM))[threadIdx.x] = o;
}

// ---------------- generic C = A @ Bt^T + bias, bf16 in / fp32 out ----------------
// A: MxK bf16 row-major; Bt: NxK bf16 row-major; C: MxN fp32. K multiple of 32, M multiple of 64.
__global__ __launch_bounds__(256) void gemm_bt_bias(const unsigned short* __restrict__ A,
                                                    const unsigned short* __restrict__ Bt,
                                                    const float* __restrict__ bias,
                                                    float* __restrict__ C,
                                                    int M, int N, int K) {
    __shared__ unsigned short As[64 * 40];
    __shared__ unsigned short Bs[64 * 40];
    int rowBase = blockIdx.y * 64;
    int colBase = blockIdx.x * 64;
    int tid = threadIdx.x;
    int wave = tid >> 6, lane = tid & 63;
    int wr = wave >> 1, wc = wave & 1;
    int quad = lane >> 4, lr = lane & 15;
    int ldRow = tid >> 2;            // 0..63
    int ldK = (tid & 3) * 8;         // 0,8,16,24
    bool bvalid = (colBase + ldRow) < N;
    const unsigned short* Ag = A + (size_t)(rowBase + ldRow) * K + ldK;
    const unsigned short* Bg = Bt + (size_t)(colBase + ldRow) * K + ldK;

    f32x4 acc[2][2] = {};
    for (int k0 = 0; k0 < K; k0 += 32) {
        uint4 av = *(const uint4*)(Ag + k0);
        uint4 bv = {};
        if (bvalid) bv = *(const uint4*)(Bg + k0);
        __syncthreads();
        *(uint4*)(As + ldRow * 40 + ldK) = av;
        *(uint4*)(Bs + ldRow * 40 + ldK) = bv;
        __syncthreads();
        bf16x8 a0 = *(const bf16x8*)(As + (wr * 32 + lr) * 40 + quad * 8);
        bf16x8 a1 = *(const bf16x8*)(As + (wr * 32 + 16 + lr) * 40 + quad * 8);
        bf16x8 b0 = *(const bf16x8*)(Bs + (wc * 32 + lr) * 40 + quad * 8);
        bf16x8 b1 = *(const bf16x8*)(Bs + (wc * 32 + 16 + lr) * 40 + quad * 8);
        acc[0][0] = __builtin_amdgcn_mfma_f32_16x16x32_bf16(a0, b0, acc[0][0], 0, 0, 0);
        acc[0][1] = __builtin_amdgcn_mfma_f32_16x16x32_bf16(a0, b1, acc[0][1], 0, 0, 0);
        acc[1][0] = __builtin_amdgcn_mfma_f32_16x16x32_bf16(a1, b0, acc[1][0], 0, 0, 0);
        acc[1][1] = __builtin_amdgcn_mfma_f32_16x16x32_bf16(a1, b1, acc[1][1], 0, 0, 0);
    }
    for (int mi = 0; mi < 2; mi++)
        for (int ni = 0; ni < 2; ni++) {
            int col = colBase + wc * 32 + ni * 16 + lr;
            if (col < N) {
                float b = bias[col];
                for (int r = 0; r < 4; r++) {
                    int row = rowBase + wr * 32 + mi * 16 + quad * 4 + r;
                    C[(size_t)row * N + col] = acc[mi][ni][r] + b;
                }
            }
        }
}

// ---------------- h0 recurrence + gates (fp32 exact, one WG per batch row) ----------------
__global__ __launch_bounds__(128) void h0_chain(const float* __restrict__ Xa,   // (T*B) x 128
                                                const float* __restrict__ Wah,  // 128 x 128
                                                const float* __restrict__ Wa,   // 128 x 2
                                                const float* __restrict__ ba,   // 2
                                                float2* __restrict__ ns) {      // T*B
    int b = blockIdx.x;      // batch 0..63
    int j = threadIdx.x;     // 0..127
    __shared__ float WahS[HADIM * HADIM];
    __shared__ float h0s[HADIM];
    __shared__ float red[4];
    for (int i = j; i < HADIM * HADIM; i += 128) WahS[i] = Wah[i];
    h0s[j] = 0.f;
    float wa0 = Wa[j * 2 + 0], wa1 = Wa[j * 2 + 1];
    float ba0 = ba[0], ba1 = ba[1];
    __syncthreads();
    for (int t = 0; t < TSTEPS; t++) {
        float acc = Xa[((size_t)t * BATCH + b) * HADIM + j];
        for (int k = 0; k < HADIM; k++) acc += h0s[k] * WahS[k * HADIM + j];
        float h0n = tanhf(acc);
        float p0 = h0n * wa0, p1 = h0n * wa1;
        for (int off = 32; off > 0; off >>= 1) {
            p0 += __shfl_down(p0, off);
            p1 += __shfl_down(p1, off);
        }
        int wv = j >> 6;
        if ((j & 63) == 0) { red[wv * 2 + 0] = p0; red[wv * 2 + 1] = p1; }
        __syncthreads();
        float n = 1.f / (1.f + __expf(-(red[0] + red[2] + ba0)));
        float s = 1.f / (1.f + __expf(-(red[1] + red[3] + ba1)));
        if (j == 0) ns[t * BATCH + b] = make_float2(n, s);
        h0s[j] = h0n;
        __syncthreads();
    }
}

// ---------------- fused h1 recurrence: ALL 128 steps, custom fast grid barrier ----------------
// grid = 32 blocks x 512 threads (8 waves). Block cg owns output cols [cg*32, cg*32+32).
// Weights for the block's 32 cols live in LDS (64 KB, XOR-swizzled), staged ONCE.
// Swapped MFMA operands (A=weights m=outcol, B=h n=batchrow) => each lane's C holds
// 4 CONSECUTIVE out-cols of one batch row: hs write = one 8B agent-scope store,
// Xi read = one float4, gates = one float2.
// Coherence: hs stores are agent-scope (sc0 sc1, write-through to LLC, bypass the
// non-coherent per-XCD L2). Each 64B hs line is written by exactly one block and
// first read only after the barrier, so plain cached loads are safe for reads.
// Barrier: monotonic agent-scope atomic counter; no cache-maintenance ops.
__global__ __launch_bounds__(512, 2) void rnn_fused(
        const unsigned short* __restrict__ WhhT,  // 1024x1024 bf16 (N x K)
        const float* __restrict__ Xi,             // (T*B) x 1024 fp32  (x@Wih + bh)
        const float2* __restrict__ ns,            // T*B gates (n,s)
        unsigned short* __restrict__ hs,          // (T*B) x 1024 bf16
        float* __restrict__ h1f,                  // 64x1024 fp32 (final h1)
        unsigned int* __restrict__ bar) {         // barrier counter (zeroed per launch)
    __shared__ unsigned short Ws[32 * HDIM];      // 64 KB weight slice, swizzled
    const int cgid = blockIdx.x;                  // 0..31
    const int tid  = threadIdx.x;
    const int wave = tid >> 6;                    // 0..7
    const int lane = tid & 63;
    const int bm   = wave & 3;                    // batch-row tile (16 rows)
    const int nt   = wave >> 2;                   // col sub-tile (0/1)
    const int quad = lane >> 4, lr = lane & 15;
    const int colBase = cgid * 32;

    // ---- stage weight slice into LDS, XOR-swizzled (byte ^= (row&7)<<4) ----
    for (int i = 0; i < 8; i++) {
        int c   = tid + i * 512;                  // 16B-chunk id, 0..4095
        int row = c >> 7;                         // 0..31  (local out-col)
        int cin = c & 127;                        // chunk within row
        uint4 w = *(const uint4*)(WhhT + (((size_t)(colBase + row)) << 10) + cin * 8);
        int b = (cin * 16) ^ ((row & 7) << 4);
        *(uint4*)((char*)Ws + row * 2048 + b) = w;
    }

    const int batchrow = bm * 16 + lr;                 // 0..63
    const int colq = colBase + nt * 16 + quad * 4;     // 4 consecutive out-cols
    const int wrow = nt * 16 + lr;                     // LDS row for A-frags
    const char* wbase = (const char*)Ws + wrow * 2048;
    const int rb = (wrow & 7) << 4;

    // prefetch t=0 inputs
    float4 xi_v = *(const float4*)(Xi + (size_t)batchrow * HDIM + colq);
    float2 g_v  = ns[batchrow];
    __syncthreads();                                   // weights staged

    for (int t = 0; t < TSTEPS; t++) {
        f32x4 acc[4] = {};
        if (t > 0) {
            const char* hb = (const char*)(hs + ((size_t)(t - 1) * BATCH + batchrow) * HDIM)
                             + quad * 16;
            uint4 hv[32];
            #pragma unroll
            for (int i = 0; i < 32; i++) hv[i] = *(const uint4*)(hb + i * 64);
            #pragma unroll
            for (int kc = 0; kc < 32; kc++) {
                bf16x8 wf = *(const bf16x8*)(wbase + ((kc * 64 + quad * 16) ^ rb));
                acc[kc & 3] = __builtin_amdgcn_mfma_f32_16x16x32_bf16(
                                  wf, *(const bf16x8*)&hv[kc], acc[kc & 3], 0, 0, 0);
            }
        }
        f32x4 a = (acc[0] + acc[1]) + (acc[2] + acc[3]);
        float h1n[4];
        #pragma unroll
        for (int r = 0; r < 4; r++) {
            float pre = a[r] + ((const float*)&xi_v)[r];
            float z  = g_v.x * pre;
            float th = tanhf(z);
            float sg = 1.f / (1.f + __expf(-z));
            h1n[r] = (1.f - g_v.y) * th + g_v.y * sg;
        }
        unsigned long long pk =
              (unsigned long long)f2bf(h1n[0])
            | ((unsigned long long)f2bf(h1n[1]) << 16)
            | ((unsigned long long)f2bf(h1n[2]) << 32)
            | ((unsigned long long)f2bf(h1n[3]) << 48);
        __hip_atomic_store((unsigned long long*)(hs + ((size_t)t * BATCH + batchrow) * HDIM + colq),
                           pk, __ATOMIC_RELAXED, __HIP_MEMORY_SCOPE_AGENT);
        if (t == TSTEPS - 1) {
            *(float4*)(h1f + (size_t)batchrow * HDIM + colq) =
                make_float4(h1n[0], h1n[1], h1n[2], h1n[3]);
        } else {
            // prefetch next step's inputs (hides under the store drain + barrier)
            xi_v = *(const float4*)(Xi + ((size_t)(t + 1) * BATCH + batchrow) * HDIM + colq);
            g_v  = ns[(t + 1) * BATCH + batchrow];
            asm volatile("s_waitcnt vmcnt(0)" ::: "memory");  // hs stores at LLC
            __syncthreads();
            if (tid == 0) {
                __hip_atomic_fetch_add(bar, 1u, __ATOMIC_RELAXED, __HIP_MEMORY_SCOPE_AGENT);
                unsigned need = (unsigned)(t + 1) * NBLK;
                while (__hip_atomic_load(bar, __ATOMIC_RELAXED, __HIP_MEMORY_SCOPE_AGENT) < need) {}
            }
            __syncthreads();
        }
    }
}

extern "C" void kernel_launch(void* const* d_in, const int* in_sizes, int n_in,
                              void* d_out, int out_size, void* d_ws, size_t ws_size,
                              hipStream_t stream) {
    const int*   tokens = (const int*)d_in[0];
    const float* emb    = (const float*)d_in[1];
    const float* Wax    = (const float*)d_in[2];
    const float* Wah    = (const float*)d_in[3];
    const float* bah    = (const float*)d_in[4];
    const float* Wa     = (const float*)d_in[5];
    const float* ba     = (const float*)d_in[6];
    const float* Wih    = (const float*)d_in[7];
    const float* Whh    = (const float*)d_in[8];
    const float* bh     = (const float*)d_in[9];
    const float* Wd     = (const float*)d_in[10];
    const float* bd     = (const float*)d_in[11];
    float* out = (float*)d_out;

    char* ws = (char*)d_ws;
    size_t off = 0;
    auto alloc = [&](size_t bytes) -> void* {
        void* p = ws + off;
        off += (bytes + 255) & ~(size_t)255;
        return p;
    };
    unsigned short* WihT = (unsigned short*)alloc((size_t)HDIM * DDIM * 2);      // 2 MB
    unsigned short* WaxT = (unsigned short*)alloc((size_t)HADIM * DDIM * 2);     // 256 KB
    unsigned short* WhhT = (unsigned short*)alloc((size_t)HDIM * HDIM * 2);      // 2 MB
    unsigned short* WdT  = (unsigned short*)alloc((size_t)VOCAB * HDIM * 2);     // ~20 MB
    unsigned short* xb   = (unsigned short*)alloc((size_t)MROWS * DDIM * 2);     // 16 MB
    float*          Xi   = (float*)alloc((size_t)MROWS * HDIM * 4);              // 32 MB
    float*          Xa   = (float*)alloc((size_t)MROWS * HADIM * 4);             // 4 MB
    unsigned short* hs   = (unsigned short*)alloc((size_t)MROWS * HDIM * 2);     // 16 MB
    float2*         ns   = (float2*)alloc((size_t)TSTEPS * BATCH * 8);           // 64 KB
    unsigned int*   bar  = (unsigned int*)alloc(256);                            // barrier counter

    // 1. weight transposes (fp32 -> bf16, B^T layout for GEMMs)
    transpose_cast<<<dim3(32, 32), 256, 0, stream>>>(Wih, WihT, DDIM, HDIM);
    transpose_cast<<<dim3(4, 32), 256, 0, stream>>>(Wax, WaxT, DDIM, HADIM);
    transpose_cast<<<dim3(32, 32), 256, 0, stream>>>(Whh, WhhT, HDIM, HDIM);
    transpose_cast<<<dim3(313, 32), 256, 0, stream>>>(Wd, WdT, HDIM, VOCAB);
    // 2. gather x = emb[tokens] -> bf16
    gather_cast<<<MROWS, 256, 0, stream>>>(tokens, emb, xb);
    // 3. Xi = x @ Wih + bh ; Xa = x @ Wax + bah
    gemm_bt_bias<<<dim3(HDIM / 64, MROWS / 64), 256, 0, stream>>>(xb, WihT, bh, Xi, MROWS, HDIM, DDIM);
    gemm_bt_bias<<<dim3(HADIM / 64, MROWS / 64), 256, 0, stream>>>(xb, WaxT, bah, Xa, MROWS, HADIM, DDIM);
    // 4. h0 chain + gates (all timesteps)
    h0_chain<<<BATCH, 128, 0, stream>>>(Xa, Wah, Wa, ba, ns);
    // 5. fused h1 recurrence (barrier counter must be zeroed every launch/replay)
    hipMemsetAsync(bar, 0, sizeof(unsigned int), stream);
    {
        float* h1fin = out + (size_t)MROWS * VOCAB;
        const unsigned short* WhhT_a = WhhT;
        const float*  Xi_a = Xi;
        const float2* ns_a = ns;
        unsigned short* hs_a = hs;
        unsigned int* bar_a = bar;
        void* args[] = { (void*)&WhhT_a, (void*)&Xi_a, (void*)&ns_a, (void*)&hs_a,
                         (void*)&h1fin, (void*)&bar_a };
        hipLaunchCooperativeKernel((const void*)rnn_fused, dim3(NBLK), dim3(512), args, 0, stream);
    }
    // 6. decoded = hs @ Wd + bd
    gemm_bt_bias<<<dim3((VOCAB + 63) / 64, MROWS / 64), 256, 0, stream>>>(hs, WdT, bd, out, MROWS, VOCAB, HDIM);
}

// Round 3
// 2202.672 us; speedup vs baseline: 1.4434x; 1.1006x over previous
//
#include <hip/hip_runtime.h>
#include <hip/hip_bf16.h>
#include <cstdint>
#include <cstddef>

// Problem dims (fixed)
#define TSTEPS 128
#define BATCH  64
#define DDIM   1024
#define HDIM   1024
#define HADIM  128
#define VOCAB  10000
#define MROWS  (TSTEPS * BATCH)   // 8192
#define CBLK   64                 // blocks in the fused recurrence grid (16 cols each)

typedef __attribute__((ext_vector_type(8))) short bf16x8;
typedef __attribute__((ext_vector_type(4))) float f32x4;

__device__ __forceinline__ unsigned short f2bf(float x) {
    unsigned int u = __float_as_uint(x);
    unsigned int r = (u + 0x7fffu + ((u >> 16) & 1u)) >> 16;
    return (unsigned short)r;
}

// ---------------- transpose + cast fp32 -> bf16 (W: RxC -> Wt: CxR) ----------------
__global__ __launch_bounds__(256) void transpose_cast(const float* __restrict__ W,
                                                      unsigned short* __restrict__ Wt,
                                                      int R, int C) {
    __shared__ float tile[32][33];
    int tc = blockIdx.x * 32;   // col base in W
    int tr = blockIdx.y * 32;   // row base in W
    int tid = threadIdx.x;
    for (int i = 0; i < 4; i++) {
        int idx = tid + i * 256;
        int r = idx >> 5, c = idx & 31;
        float v = 0.f;
        if (tr + r < R && tc + c < C) v = W[(size_t)(tr + r) * C + tc + c];
        tile[r][c] = v;
    }
    __syncthreads();
    for (int i = 0; i < 4; i++) {
        int idx = tid + i * 256;
        int r = idx >> 5, c = idx & 31;   // r = row of Wt (= col of W)
        if (tc + r < C && tr + c < R)
            Wt[(size_t)(tc + r) * R + tr + c] = f2bf(tile[c][r]);
    }
}

// ---------------- gather embedding rows + cast to bf16 ----------------
__global__ __launch_bounds__(256) void gather_cast(const int* __restrict__ tok,
                                                   const float* __restrict__ emb,
                                                   unsigned short* __restrict__ xb) {
    int i = blockIdx.x;               // 0..8191 (t*64+b)
    int t = tok[i];
    const float4* src = (const float4*)(emb + (size_t)t * DDIM);
    float4 v = src[threadIdx.x];
    ushort4 o;
    o.x = f2bf(v.x); o.y = f2bf(v.y); o.z = f2bf(v.z); o.w = f2bf(v.w);
    ((ushort4*)(xb + (size_t)i * DDIM))[threadIdx.x] = o;
}

// ---------------- generic C = A @ Bt^T + bias, bf16 in / fp32 out ----------------
// A: MxK bf16 row-major; Bt: NxK bf16 row-major; C: MxN fp32. K multiple of 32, M multiple of 64.
__global__ __launch_bounds__(256) void gemm_bt_bias(const unsigned short* __restrict__ A,
                                                    const unsigned short* __restrict__ Bt,
                                                    const float* __restrict__ bias,
                                                    float* __restrict__ C,
                                                    int M, int N, int K) {
    __shared__ unsigned short As[64 * 40];
    __shared__ unsigned short Bs[64 * 40];
    int rowBase = blockIdx.y * 64;
    int colBase = blockIdx.x * 64;
    int tid = threadIdx.x;
    int wave = tid >> 6, lane = tid & 63;
    int wr = wave >> 1, wc = wave & 1;
    int quad = lane >> 4, lr = lane & 15;
    int ldRow = tid >> 2;            // 0..63
    int ldK = (tid & 3) * 8;         // 0,8,16,24
    bool bvalid = (colBase + ldRow) < N;
    const unsigned short* Ag = A + (size_t)(rowBase + ldRow) * K + ldK;
    const unsigned short* Bg = Bt + (size_t)(colBase + ldRow) * K + ldK;

    f32x4 acc[2][2] = {};
    for (int k0 = 0; k0 < K; k0 += 32) {
        uint4 av = *(const uint4*)(Ag + k0);
        uint4 bv = {};
        if (bvalid) bv = *(const uint4*)(Bg + k0);
        __syncthreads();
        *(uint4*)(As + ldRow * 40 + ldK) = av;
        *(uint4*)(Bs + ldRow * 40 + ldK) = bv;
        __syncthreads();
        bf16x8 a0 = *(const bf16x8*)(As + (wr * 32 + lr) * 40 + quad * 8);
        bf16x8 a1 = *(const bf16x8*)(As + (wr * 32 + 16 + lr) * 40 + quad * 8);
        bf16x8 b0 = *(const bf16x8*)(Bs + (wc * 32 + lr) * 40 + quad * 8);
        bf16x8 b1 = *(const bf16x8*)(Bs + (wc * 32 + 16 + lr) * 40 + quad * 8);
        acc[0][0] = __builtin_amdgcn_mfma_f32_16x16x32_bf16(a0, b0, acc[0][0], 0, 0, 0);
        acc[0][1] = __builtin_amdgcn_mfma_f32_16x16x32_bf16(a0, b1, acc[0][1], 0, 0, 0);
        acc[1][0] = __builtin_amdgcn_mfma_f32_16x16x32_bf16(a1, b0, acc[1][0], 0, 0, 0);
        acc[1][1] = __builtin_amdgcn_mfma_f32_16x16x32_bf16(a1, b1, acc[1][1], 0, 0, 0);
    }
    for (int mi = 0; mi < 2; mi++)
        for (int ni = 0; ni < 2; ni++) {
            int col = colBase + wc * 32 + ni * 16 + lr;
            if (col < N) {
                float b = bias[col];
                for (int r = 0; r < 4; r++) {
                    int row = rowBase + wr * 32 + mi * 16 + quad * 4 + r;
                    C[(size_t)row * N + col] = acc[mi][ni][r] + b;
                }
            }
        }
}

// ---------------- h0 recurrence + gates (fp32 exact, one WG per batch row) ----------------
__global__ __launch_bounds__(128) void h0_chain(const float* __restrict__ Xa,   // (T*B) x 128
                                                const float* __restrict__ Wah,  // 128 x 128
                                                const float* __restrict__ Wa,   // 128 x 2
                                                const float* __restrict__ ba,   // 2
                                                float2* __restrict__ ns) {      // T*B
    int b = blockIdx.x;      // batch 0..63
    int j = threadIdx.x;     // 0..127
    __shared__ float WahS[HADIM * HADIM];
    __shared__ float h0s[HADIM];
    __shared__ float red[4];
    for (int i = j; i < HADIM * HADIM; i += 128) WahS[i] = Wah[i];
    h0s[j] = 0.f;
    float wa0 = Wa[j * 2 + 0], wa1 = Wa[j * 2 + 1];
    float ba0 = ba[0], ba1 = ba[1];
    __syncthreads();
    for (int t = 0; t < TSTEPS; t++) {
        float acc = Xa[((size_t)t * BATCH + b) * HADIM + j];
        for (int k = 0; k < HADIM; k++) acc += h0s[k] * WahS[k * HADIM + j];
        float h0n = tanhf(acc);
        float p0 = h0n * wa0, p1 = h0n * wa1;
        for (int off = 32; off > 0; off >>= 1) {
            p0 += __shfl_down(p0, off);
            p1 += __shfl_down(p1, off);
        }
        int wv = j >> 6;
        if ((j & 63) == 0) { red[wv * 2 + 0] = p0; red[wv * 2 + 1] = p1; }
        __syncthreads();
        float n = 1.f / (1.f + __expf(-(red[0] + red[2] + ba0)));
        float s = 1.f / (1.f + __expf(-(red[1] + red[3] + ba1)));
        if (j == 0) ns[t * BATCH + b] = make_float2(n, s);
        h0s[j] = h0n;
        __syncthreads();
    }
}

// ---------------- fused h1 recurrence: ALL 128 steps, flag-array grid barrier ----------------
// grid = 64 blocks x 512 threads (8 waves). Block owns output cols [blk*16, blk*16+16).
// Waves: bm = wave&3 (16 batch rows each), kh = wave>>2 (K-half 0/1).
// Weights (16 cols x 1024 K) live in LDS, CONFLICT-FREE layout [kc][quad][row] so a
// wave's read is one contiguous 1KB span. K-halves reduced via 4KB LDS.
// h-loads: hv[16] (64 VGPR) with sched_barrier(0) pin => all 16 loads in flight.
// Coherence (validated in round 2): hs stores are agent-scope (write-through to LLC);
// each hs address is written by one block and first read only after the barrier.
// Barrier: per-block flag line store + 64-lane parallel poll with __all.
__global__ __launch_bounds__(512, 2) void rnn_fused(
        const unsigned short* __restrict__ WhhT,  // 1024x1024 bf16 (N x K)
        const float* __restrict__ Xi,             // (T*B) x 1024 fp32  (x@Wih + bh)
        const float2* __restrict__ ns,            // T*B gates (n,s)
        unsigned short* __restrict__ hs,          // (T*B) x 1024 bf16
        float* __restrict__ h1f,                  // 64x1024 fp32 (final h1)
        unsigned int* __restrict__ flags) {       // CBLK flags (zeroed per launch)
    __shared__ unsigned short Ws[16 * HDIM];          // 32 KB weight slice
    __shared__ __align__(16) float red[4 * 64 * 4];   // 4 KB kh-reduce buffer
    const int cgid = blockIdx.x;                  // 0..63
    const int tid  = threadIdx.x;
    const int wave = tid >> 6;                    // 0..7
    const int lane = tid & 63;
    const int kh   = wave >> 2;                   // K-half
    const int bm   = wave & 3;                    // batch-row tile
    const int quad = lane >> 4, lr = lane & 15;
    const int colBase = cgid * 16;

    // ---- stage weight slice into LDS, layout chunk[(cin>>2)*64 + (cin&3)*16 + row] ----
    // (wave read of fragment j is then 64 consecutive 16B chunks = conflict-free)
    for (int i = 0; i < 4; i++) {
        int c   = tid + i * 512;                  // 0..2047 16B-chunks
        int row = c >> 7;                         // 0..15 (local out-col)
        int cin = c & 127;                        // k-chunk of 8 elems
        uint4 w = *(const uint4*)(WhhT + (((size_t)(colBase + row)) << 10) + cin * 8);
        *(uint4*)((char*)Ws + (((cin >> 2) * 64 + (cin & 3) * 16 + row) << 4)) = w;
    }

    const int batchrow = bm * 16 + lr;            // 0..63
    const int colq = colBase + quad * 4;          // 4 consecutive out-cols (kh==0 epilogue)
    __syncthreads();                              // weights staged

    for (int t = 0; t < TSTEPS; t++) {
        float4 xi_v = {};
        float2 g_v  = {};
        if (kh == 0) {                            // epilogue inputs (hidden under MFMA phase)
            xi_v = *(const float4*)(Xi + ((size_t)t * BATCH + batchrow) * HDIM + colq);
            g_v  = ns[t * BATCH + batchrow];
        }
        f32x4 acc[4] = {};
        if (t > 0) {
            const unsigned short* hbase = hs + ((size_t)(t - 1) * BATCH + batchrow) * HDIM
                                          + kh * 512 + quad * 8;
            uint4 hv[16];
            #pragma unroll
            for (int i = 0; i < 16; i++) hv[i] = *(const uint4*)(hbase + i * 32);
            __builtin_amdgcn_sched_barrier(0);    // pin: all 16 loads issued before MFMAs
            #pragma unroll
            for (int j = 0; j < 16; j++) {
                bf16x8 wf = *(const bf16x8*)((const char*)Ws +
                                ((((kh * 16 + j) * 64 + quad * 16 + lr)) << 4));
                acc[j & 3] = __builtin_amdgcn_mfma_f32_16x16x32_bf16(
                                 wf, *(const bf16x8*)&hv[j], acc[j & 3], 0, 0, 0);
            }
        }
        f32x4 a = (acc[0] + acc[1]) + (acc[2] + acc[3]);
        if (kh == 1) *(f32x4*)&red[(bm * 64 + lane) * 4] = a;
        __syncthreads();                          // kh=1 partials visible
        if (kh == 0) {
            a += *(const f32x4*)&red[(bm * 64 + lane) * 4];
            float h1n[4];
            #pragma unroll
            for (int r = 0; r < 4; r++) {
                float pre = a[r] + ((const float*)&xi_v)[r];
                float z  = g_v.x * pre;
                float th = tanhf(z);
                float sg = 1.f / (1.f + __expf(-z));
                h1n[r] = (1.f - g_v.y) * th + g_v.y * sg;
            }
            unsigned long long pk =
                  (unsigned long long)f2bf(h1n[0])
                | ((unsigned long long)f2bf(h1n[1]) << 16)
                | ((unsigned long long)f2bf(h1n[2]) << 32)
                | ((unsigned long long)f2bf(h1n[3]) << 48);
            __hip_atomic_store((unsigned long long*)(hs + ((size_t)t * BATCH + batchrow) * HDIM + colq),
                               pk, __ATOMIC_RELAXED, __HIP_MEMORY_SCOPE_AGENT);
            if (t == TSTEPS - 1)
                *(float4*)(h1f + (size_t)batchrow * HDIM + colq) =
                    make_float4(h1n[0], h1n[1], h1n[2], h1n[3]);
        }
        if (t < TSTEPS - 1) {
            asm volatile("s_waitcnt vmcnt(0)" ::: "memory");  // hs stores at LLC
            __syncthreads();                                  // whole block drained
            if (wave == 0) {
                if (lane == 0)
                    __hip_atomic_store(&flags[cgid], (unsigned)(t + 1),
                                       __ATOMIC_RELAXED, __HIP_MEMORY_SCOPE_AGENT);
                unsigned need = (unsigned)(t + 1);
                while (true) {
                    unsigned v = __hip_atomic_load(&flags[lane],
                                                   __ATOMIC_RELAXED, __HIP_MEMORY_SCOPE_AGENT);
                    if (__all(v >= need)) break;
                    __builtin_amdgcn_s_sleep(1);
                }
            }
            __syncthreads();                                  // barrier released
        }
    }
}

extern "C" void kernel_launch(void* const* d_in, const int* in_sizes, int n_in,
                              void* d_out, int out_size, void* d_ws, size_t ws_size,
                              hipStream_t stream) {
    const int*   tokens = (const int*)d_in[0];
    const float* emb    = (const float*)d_in[1];
    const float* Wax    = (const float*)d_in[2];
    const float* Wah    = (const float*)d_in[3];
    const float* bah    = (const float*)d_in[4];
    const float* Wa     = (const float*)d_in[5];
    const float* ba     = (const float*)d_in[6];
    const float* Wih    = (const float*)d_in[7];
    const float* Whh    = (const float*)d_in[8];
    const float* bh     = (const float*)d_in[9];
    const float* Wd     = (const float*)d_in[10];
    const float* bd     = (const float*)d_in[11];
    float* out = (float*)d_out;

    char* ws = (char*)d_ws;
    size_t off = 0;
    auto alloc = [&](size_t bytes) -> void* {
        void* p = ws + off;
        off += (bytes + 255) & ~(size_t)255;
        return p;
    };
    unsigned short* WihT = (unsigned short*)alloc((size_t)HDIM * DDIM * 2);      // 2 MB
    unsigned short* WaxT = (unsigned short*)alloc((size_t)HADIM * DDIM * 2);     // 256 KB
    unsigned short* WhhT = (unsigned short*)alloc((size_t)HDIM * HDIM * 2);      // 2 MB
    unsigned short* WdT  = (unsigned short*)alloc((size_t)VOCAB * HDIM * 2);     // ~20 MB
    unsigned short* xb   = (unsigned short*)alloc((size_t)MROWS * DDIM * 2);     // 16 MB
    float*          Xi   = (float*)alloc((size_t)MROWS * HDIM * 4);              // 32 MB
    float*          Xa   = (float*)alloc((size_t)MROWS * HADIM * 4);             // 4 MB
    unsigned short* hs   = (unsigned short*)alloc((size_t)MROWS * HDIM * 2);     // 16 MB
    float2*         ns   = (float2*)alloc((size_t)TSTEPS * BATCH * 8);           // 64 KB
    unsigned int*   flags= (unsigned int*)alloc(CBLK * sizeof(unsigned int));    // barrier flags

    // 1. weight transposes (fp32 -> bf16, B^T layout for GEMMs)
    transpose_cast<<<dim3(32, 32), 256, 0, stream>>>(Wih, WihT, DDIM, HDIM);
    transpose_cast<<<dim3(4, 32), 256, 0, stream>>>(Wax, WaxT, DDIM, HADIM);
    transpose_cast<<<dim3(32, 32), 256, 0, stream>>>(Whh, WhhT, HDIM, HDIM);
    transpose_cast<<<dim3(313, 32), 256, 0, stream>>>(Wd, WdT, HDIM, VOCAB);
    // 2. gather x = emb[tokens] -> bf16
    gather_cast<<<MROWS, 256, 0, stream>>>(tokens, emb, xb);
    // 3. Xi = x @ Wih + bh ; Xa = x @ Wax + bah
    gemm_bt_bias<<<dim3(HDIM / 64, MROWS / 64), 256, 0, stream>>>(xb, WihT, bh, Xi, MROWS, HDIM, DDIM);
    gemm_bt_bias<<<dim3(HADIM / 64, MROWS / 64), 256, 0, stream>>>(xb, WaxT, bah, Xa, MROWS, HADIM, DDIM);
    // 4. h0 chain + gates (all timesteps)
    h0_chain<<<BATCH, 128, 0, stream>>>(Xa, Wah, Wa, ba, ns);
    // 5. fused h1 recurrence (flags must be zeroed every launch/replay)
    hipMemsetAsync(flags, 0, CBLK * sizeof(unsigned int), stream);
    {
        float* h1fin = out + (size_t)MROWS * VOCAB;
        const unsigned short* WhhT_a = WhhT;
        const float*  Xi_a = Xi;
        const float2* ns_a = ns;
        unsigned short* hs_a = hs;
        unsigned int* flags_a = flags;
        void* args[] = { (void*)&WhhT_a, (void*)&Xi_a, (void*)&ns_a, (void*)&hs_a,
                         (void*)&h1fin, (void*)&flags_a };
        hipLaunchCooperativeKernel((const void*)rnn_fused, dim3(CBLK), dim3(512), args, 0, stream);
    }
    // 6. decoded = hs @ Wd + bd
    gemm_bt_bias<<<dim3((VOCAB + 63) / 64, MROWS / 64), 256, 0, stream>>>(hs, WdT, bd, out, MROWS, VOCAB, HDIM);
}